// Round 1
// baseline (354.204 us; speedup 1.0000x reference)
//
#include <hip/hip_runtime.h>

#define N_NODES 100000
#define N_EDGES 1600000
#define HIDDEN 64

// One wave (64 lanes) per edge; lane index = hidden dim.
// Edge metadata (row/col/val) is wave-uniform -> scalar loads.
// x gather is a coalesced 256B read per wave; scatter via fp32 atomicAdd.
__global__ void spmm_scatter_kernel(const float* __restrict__ x,
                                    const int* __restrict__ rows,
                                    const int* __restrict__ cols,
                                    const float* __restrict__ vals,
                                    float* __restrict__ f) {
    const int lane = threadIdx.x & 63;
    const int wave = (blockIdx.x * blockDim.x + threadIdx.x) >> 6;
    const int nWaves = (gridDim.x * blockDim.x) >> 6;
    for (int e = wave; e < N_EDGES; e += nWaves) {
        const int r = rows[e];
        const int c = cols[e];
        const float v = vals[e];
        const float xv = x[c * HIDDEN + lane];
        atomicAdd(&f[r * HIDDEN + lane], v * xv);
    }
}

// In-place ReLU over the accumulated output (float4-vectorized).
__global__ void relu_inplace_kernel(float4* __restrict__ f, int n4) {
    int i = blockIdx.x * blockDim.x + threadIdx.x;
    const int stride = gridDim.x * blockDim.x;
    for (; i < n4; i += stride) {
        float4 v = f[i];
        v.x = fmaxf(v.x, 0.0f);
        v.y = fmaxf(v.y, 0.0f);
        v.z = fmaxf(v.z, 0.0f);
        v.w = fmaxf(v.w, 0.0f);
        f[i] = v;
    }
}

extern "C" void kernel_launch(void* const* d_in, const int* in_sizes, int n_in,
                              void* d_out, int out_size, void* d_ws, size_t ws_size,
                              hipStream_t stream) {
    // inputs: [0]=t (scalar f32), [1]=x [N,H] f32, [2]=A_rows i32,
    //         [3]=A_cols i32, [4]=A_vals f32
    const float* x    = (const float*)d_in[1];
    const int*   rows = (const int*)d_in[2];
    const int*   cols = (const int*)d_in[3];
    const float* vals = (const float*)d_in[4];
    float* out = (float*)d_out;

    // Zero accumulator (d_out) — harness does not re-poison between replays.
    hipMemsetAsync(d_out, 0, (size_t)N_NODES * HIDDEN * sizeof(float), stream);

    // Scatter: fill the machine (256 CU * 32 waves = 8192 waves).
    const int block = 256;
    const int grid = 2048;  // 8192 waves, ~196 edges each
    spmm_scatter_kernel<<<grid, block, 0, stream>>>(x, rows, cols, vals, out);

    // ReLU in place.
    const int n4 = (N_NODES * HIDDEN) / 4;
    const int rblock = 256;
    const int rgrid = 2048;
    relu_inplace_kernel<<<rgrid, rblock, 0, stream>>>((float4*)d_out, n4);
}